// Round 1
// baseline (79204.962 us; speedup 1.0000x reference)
//
#include <hip/hip_runtime.h>
#include <hip/hip_bf16.h>
#include <math.h>

// Problem constants
#define NB    32    // batch
#define NSEED 128
#define NTT   512   // total timesteps (128 seed + 384 gen)
#define NIN   171
#define NINP  192   // padded input dim (6 k-tiles of 32)
#define NH    1024
#define NG    4096  // 4*H
#define NOUT  171
#define NOUTP 176   // padded to 11 n-tiles of 16
#define NWG   256

typedef unsigned short u16;
typedef __attribute__((ext_vector_type(8))) short bf16x8;
typedef __attribute__((ext_vector_type(4))) float f32x4;

__device__ __host__ inline u16 f2bf(float x) {
  union { float f; unsigned u; } v; v.f = x;
  unsigned r = v.u + 0x7FFFu + ((v.u >> 16) & 1u);
  return (u16)(r >> 16);
}

// ---------------------------------------------------------------------------
// Packing: each 4096xK fp32 weight matrix -> MFMA B-fragment blobs (bf16).
// Column permute: WG w owns hidden units j in {4w..4w+3}; packed col
// c = jl*4 + gate  ->  original row r = gate*1024 + w*4 + jl.
// Blob layout: dst[(((kt*256)+nt)*64 + lane)*8 + j] = W[r][kt*32 + (lane>>4)*8 + j]
// ---------------------------------------------------------------------------
__global__ void pack_mat(const float* __restrict__ src, u16* __restrict__ dst, int ktiles) {
  int id = blockIdx.x * 256 + threadIdx.x;
  int total = ktiles * 256 * 64;
  if (id >= total) return;
  int lane = id & 63;
  int nt = (id >> 6) & 255;
  int kt = id >> 14;
  int c = lane & 15, q = lane >> 4;
  int r = (c & 3) * 1024 + nt * 4 + (c >> 2);
  int K = ktiles * 32;
  const float* s = src + (size_t)r * K + kt * 32 + q * 8;
  __attribute__((aligned(16))) u16 o[8];
#pragma unroll
  for (int j = 0; j < 8; ++j) o[j] = f2bf(s[j]);
  *(bf16x8*)(dst + (size_t)id * 8) = *(const bf16x8*)o;
}

// Wih1: [4096 x 171] padded to K=192 (6 ktiles), same permute.
__global__ void pack_wih1(const float* __restrict__ src, u16* __restrict__ dst) {
  int id = blockIdx.x * 256 + threadIdx.x;
  if (id >= 6 * 256 * 64) return;
  int lane = id & 63;
  int nt = (id >> 6) & 255;
  int kt = id >> 14;
  int c = lane & 15, q = lane >> 4;
  int r = (c & 3) * 1024 + nt * 4 + (c >> 2);
  int k0 = kt * 32 + q * 8;
  __attribute__((aligned(16))) u16 o[8];
#pragma unroll
  for (int j = 0; j < 8; ++j) {
    int k = k0 + j;
    o[j] = (k < NIN) ? f2bf(src[(size_t)r * NIN + k]) : (u16)0;
  }
  *(bf16x8*)(dst + (size_t)id * 8) = *(const bf16x8*)o;
}

// Wdec: [171 x 1024] -> B-frags for out = h3 @ Wdec^T, cols padded to 176 (11 ntiles).
// No gate permute: packed col n = nt*16 + (lane&15) is the output index.
__global__ void pack_wdec(const float* __restrict__ src, u16* __restrict__ dst) {
  int id = blockIdx.x * 256 + threadIdx.x;
  if (id >= 32 * 11 * 64) return;
  int lane = id & 63;
  int nt = (id >> 6) % 11;
  int kt = (id >> 6) / 11;
  int c = lane & 15, q = lane >> 4;
  int r = nt * 16 + c;  // output column
  int k0 = kt * 32 + q * 8;
  __attribute__((aligned(16))) u16 o[8];
#pragma unroll
  for (int j = 0; j < 8; ++j) {
    o[j] = (r < NOUT) ? f2bf(src[(size_t)r * NH + k0 + j]) : (u16)0;
  }
  *(bf16x8*)(dst + (size_t)id * 8) = *(const bf16x8*)o;
}

// seed_seq [32][128][171] fp32 -> [t][b][192] bf16, zero padded
__global__ void pack_seed(const float* __restrict__ src, u16* __restrict__ dst) {
  int id = blockIdx.x * 256 + threadIdx.x;
  if (id >= NSEED * NB * NINP) return;
  int kp = id % NINP;
  int b = (id / NINP) % NB;
  int t = id / (NINP * NB);
  float v = (kp < NIN) ? src[((size_t)b * NSEED + t) * NIN + kp] : 0.f;
  dst[id] = f2bf(v);
}

// Wfuse = Wih1 @ Wdec : [4096 x 1024] fp32 (decoder folded into layer-1 input path)
__global__ void wfuse_kernel(const float* __restrict__ wih1, const float* __restrict__ wdec,
                             float* __restrict__ tmp) {
  int n = blockIdx.x;
  int k = blockIdx.y * 256 + threadIdx.x;
  const float* wr = wih1 + (size_t)n * NIN;
  float s = 0.f;
  for (int i = 0; i < NIN; ++i) s += wr[i] * wdec[(size_t)i * NH + k];
  tmp[(size_t)n * NH + k] = s;
}

// biases, permuted to packed column order; b1g additionally folds Wih1 @ bdec
__global__ void prep_bias(const float* bih1, const float* bhh1, const float* bih2, const float* bhh2,
                          const float* bih3, const float* bhh3, const float* __restrict__ wih1,
                          const float* __restrict__ bdec_in,
                          float* b1s, float* b1g, float* b2, float* b3, float* bdecp) {
  int n = blockIdx.x * 256 + threadIdx.x;
  if (n >= NG) return;
  int wgi = n >> 4, c = n & 15;
  int r = (c & 3) * 1024 + wgi * 4 + (c >> 2);
  float v1 = bih1[r] + bhh1[r];
  b1s[n] = v1;
  float bf = 0.f;
  for (int i = 0; i < NIN; ++i) bf += wih1[(size_t)r * NIN + i] * bdec_in[i];
  b1g[n] = v1 + bf;
  b2[n] = bih2[r] + bhh2[r];
  b3[n] = bih3[r] + bhh3[r];
  if (n < NOUTP) bdecp[n] = (n < NOUT) ? bdec_in[n] : 0.f;
}

// ---------------------------------------------------------------------------
// Main persistent kernel. 256 WGs x 256 threads. WG w owns hidden units
// {4w..4w+3} of every layer. Flag-array grid barrier between stages.
// ---------------------------------------------------------------------------
__device__ inline void mm_tiles(f32x4& d0, f32x4& d1,
                                const u16* __restrict__ wpk, int wg,
                                const u16* __restrict__ xsrc, int rowstride,
                                int ktiles, int wv, int lane) {
  int m = lane & 15, q = lane >> 4;
  const u16* xa = xsrc + (size_t)m * rowstride + q * 8;
  const u16* xb = xa + (size_t)16 * rowstride;
  const u16* wb = wpk + ((size_t)wg * 64 + lane) * 8;
  for (int kt = wv; kt < ktiles; kt += 4) {       // split-K across the 4 waves
    bf16x8 bf = *(const bf16x8*)(wb + (size_t)kt * (256 * 64 * 8));
    bf16x8 a0 = *(const bf16x8*)(xa + kt * 32);
    bf16x8 a1 = *(const bf16x8*)(xb + kt * 32);
    d0 = __builtin_amdgcn_mfma_f32_16x16x32_bf16(a0, bf, d0, 0, 0, 0);
    d1 = __builtin_amdgcn_mfma_f32_16x16x32_bf16(a1, bf, d1, 0, 0, 0);
  }
}

__global__ __launch_bounds__(256, 2) void lstm_main(
    const u16* __restrict__ whh1, const u16* __restrict__ whh2, const u16* __restrict__ whh3,
    const u16* __restrict__ wih2, const u16* __restrict__ wih3,
    const u16* __restrict__ wfuse, const u16* __restrict__ wih1,
    const u16* __restrict__ seedp,
    u16* __restrict__ h1b, u16* __restrict__ h2b, u16* __restrict__ h3h,
    const float* __restrict__ b1s, const float* __restrict__ b1g,
    const float* __restrict__ b2, const float* __restrict__ b3,
    int* __restrict__ flags)
{
  int wg = blockIdx.x;
  int tid = threadIdx.x;
  int wv = tid >> 6, lane = tid & 63;
  __shared__ float red[4][64][8];     // 4-wave split-K reduction
  __shared__ float gbuf[32][16];      // gates (b, packed col)
  __shared__ float cst[3][32][4];     // cell state: layer, batch, local j
  {
    float* cp = &cst[0][0][0];
    for (int i = tid; i < 3 * 32 * 4; i += 256) cp[i] = 0.f;
  }
  __syncthreads();

  int ep = 0;
  for (int t = 0; t < NTT; ++t) {
    int par = t & 1, parp = par ^ 1;
    for (int l = 0; l < 3; ++l) {
      f32x4 d0 = {0.f, 0.f, 0.f, 0.f}, d1 = {0.f, 0.f, 0.f, 0.f};
      // phase A: recurrent term h_l[t-1] @ Whh_l^T  (skip at t==0: h=0)
      if (t > 0) {
        const u16* hs = (l == 0) ? h1b + (size_t)parp * NB * NH
                     : (l == 1) ? h2b + (size_t)parp * NB * NH
                                : h3h + (size_t)(t - 1) * NB * NH;
        const u16* wp = (l == 0) ? whh1 : (l == 1) ? whh2 : whh3;
        mm_tiles(d0, d1, wp, wg, hs, NH, 32, wv, lane);
      }
      // phase B: input term
      if (l == 0) {
        if (t < NSEED) mm_tiles(d0, d1, wih1, wg, seedp + (size_t)t * NB * NINP, NINP, 6, wv, lane);
        else           mm_tiles(d0, d1, wfuse, wg, h3h + (size_t)(t - 1) * NB * NH, NH, 32, wv, lane);
      } else {
        const u16* xs = (l == 1) ? h1b + (size_t)par * NB * NH : h2b + (size_t)par * NB * NH;
        mm_tiles(d0, d1, (l == 1) ? wih2 : wih3, wg, xs, NH, 32, wv, lane);
      }
      // reduce the 4 waves' partial D-frags via LDS
#pragma unroll
      for (int r = 0; r < 4; ++r) { red[wv][lane][r] = d0[r]; red[wv][lane][4 + r] = d1[r]; }
      __syncthreads();
      {
        int c = tid & 15, brow = tid >> 4;   // brow 0..15
        const float* bias = (l == 0) ? (t < NSEED ? b1s : b1g) : (l == 1) ? b2 : b3;
        float bv = bias[wg * 16 + c];
        int srcl = ((brow >> 2) << 4) | c;   // D-frag: col=lane&15, row=(lane>>4)*4+reg
#pragma unroll
        for (int mt = 0; mt < 2; ++mt) {
          int b = brow + mt * 16;
          int idx = mt * 4 + (brow & 3);
          gbuf[b][c] = red[0][srcl][idx] + red[1][srcl][idx] +
                       red[2][srcl][idx] + red[3][srcl][idx] + bv;
        }
      }
      __syncthreads();
      // pointwise LSTM cell for our 4 hidden units
      if (tid < 128) {
        int b = tid & 31, jl = tid >> 5;
        float gi = gbuf[b][jl * 4 + 0], gf = gbuf[b][jl * 4 + 1];
        float gg = gbuf[b][jl * 4 + 2], go = gbuf[b][jl * 4 + 3];
        float si = 1.f / (1.f + expf(-gi));
        float sf = 1.f / (1.f + expf(-gf));
        float so = 1.f / (1.f + expf(-go));
        float cn = sf * cst[l][b][jl] + si * tanhf(gg);
        cst[l][b][jl] = cn;
        float hn = so * tanhf(cn);
        u16 hb = f2bf(hn);
        size_t col = (size_t)wg * 4 + jl;
        if (l == 0)      h1b[(size_t)par * NB * NH + (size_t)b * NH + col] = hb;
        else if (l == 1) h2b[(size_t)par * NB * NH + (size_t)b * NH + col] = hb;
        else             h3h[(size_t)t * NB * NH + (size_t)b * NH + col] = hb;
      }
      // grid barrier (epoch flags; ws poison 0xAA.. is negative as int => safe)
      __threadfence();
      __syncthreads();
      ++ep;
      if (tid == 0)
        __hip_atomic_store(&flags[wg], ep, __ATOMIC_RELEASE, __HIP_MEMORY_SCOPE_AGENT);
      while (__hip_atomic_load(&flags[tid], __ATOMIC_ACQUIRE, __HIP_MEMORY_SCOPE_AGENT) < ep) {
        __builtin_amdgcn_s_sleep(1);
      }
      __syncthreads();
    }
  }
}

// ---------------------------------------------------------------------------
// Batched decoder: out[b][t][o] = h3[t] @ Wdec^T + bdec for all 512 steps.
// One wave per (row-tile of 32, n-tile of 16): 512*11 = 5632 wave tasks.
// ---------------------------------------------------------------------------
__global__ __launch_bounds__(256) void dec_kernel(
    const u16* __restrict__ h3h, const u16* __restrict__ wdec,
    const float* __restrict__ bdecp, float* __restrict__ out)
{
  int task = blockIdx.x * 4 + (threadIdx.x >> 6);
  int lane = threadIdx.x & 63;
  int nt = task % 11, rt = task / 11;
  if (rt >= NTT) return;
  int m = lane & 15, q = lane >> 4;
  const u16* xa = h3h + ((size_t)rt * 32 + m) * NH + q * 8;
  const u16* xb = xa + (size_t)16 * NH;
  f32x4 d0 = {0.f, 0.f, 0.f, 0.f}, d1 = {0.f, 0.f, 0.f, 0.f};
  for (int kt = 0; kt < 32; ++kt) {
    bf16x8 bf = *(const bf16x8*)(wdec + ((size_t)(kt * 11 + nt) * 64 + lane) * 8);
    bf16x8 a0 = *(const bf16x8*)(xa + kt * 32);
    bf16x8 a1 = *(const bf16x8*)(xb + kt * 32);
    d0 = __builtin_amdgcn_mfma_f32_16x16x32_bf16(a0, bf, d0, 0, 0, 0);
    d1 = __builtin_amdgcn_mfma_f32_16x16x32_bf16(a1, bf, d1, 0, 0, 0);
  }
  int o = nt * 16 + m;
  if (o >= NOUT) return;
  float bv = bdecp[o];
#pragma unroll
  for (int reg = 0; reg < 4; ++reg) {
    int row0 = rt * 32 + q * 4 + reg;          // row = t*32 + b
    out[(((size_t)(row0 & 31)) * NTT + (row0 >> 5)) * NOUT + o] = d0[reg] + bv;
    int row1 = row0 + 16;
    out[(((size_t)(row1 & 31)) * NTT + (row1 >> 5)) * NOUT + o] = d1[reg] + bv;
  }
}

// ---------------------------------------------------------------------------
extern "C" void kernel_launch(void* const* d_in, const int* in_sizes, int n_in,
                              void* d_out, int out_size, void* d_ws, size_t ws_size,
                              hipStream_t stream) {
  const float* seed = (const float*)d_in[0];
  const float* Wih1 = (const float*)d_in[1];
  const float* Whh1 = (const float*)d_in[2];
  const float* bih1 = (const float*)d_in[3];
  const float* bhh1 = (const float*)d_in[4];
  const float* Wih2 = (const float*)d_in[5];
  const float* Whh2 = (const float*)d_in[6];
  const float* bih2 = (const float*)d_in[7];
  const float* bhh2 = (const float*)d_in[8];
  const float* Wih3 = (const float*)d_in[9];
  const float* Whh3 = (const float*)d_in[10];
  const float* bih3 = (const float*)d_in[11];
  const float* bhh3 = (const float*)d_in[12];
  const float* Wdec = (const float*)d_in[13];
  const float* bdec = (const float*)d_in[14];

  char* ws = (char*)d_ws;
  size_t off = 0;
  auto alloc = [&](size_t bytes) -> void* {
    void* p = ws + off;
    off += (bytes + 63) & ~(size_t)63;
    return p;
  };
  const size_t BIGPK = (size_t)32 * 256 * 64 * 8 * 2;  // 8.39 MB each
  u16* whh1p  = (u16*)alloc(BIGPK);
  u16* whh2p  = (u16*)alloc(BIGPK);
  u16* whh3p  = (u16*)alloc(BIGPK);
  u16* wih2p  = (u16*)alloc(BIGPK);
  u16* wih3p  = (u16*)alloc(BIGPK);
  u16* wfusep = (u16*)alloc(BIGPK);
  u16* wih1p  = (u16*)alloc((size_t)6 * 256 * 64 * 8 * 2);
  u16* wdecp  = (u16*)alloc((size_t)32 * 11 * 64 * 8 * 2);
  u16* seedp  = (u16*)alloc((size_t)NSEED * NB * NINP * 2);
  u16* h1b    = (u16*)alloc((size_t)2 * NB * NH * 2);
  u16* h2b    = (u16*)alloc((size_t)2 * NB * NH * 2);
  u16* h3h    = (u16*)alloc((size_t)NTT * NB * NH * 2);   // 33.5 MB
  float* b1s  = (float*)alloc((size_t)NG * 4);
  float* b1g  = (float*)alloc((size_t)NG * 4);
  float* b2   = (float*)alloc((size_t)NG * 4);
  float* b3   = (float*)alloc((size_t)NG * 4);
  float* bdecp = (float*)alloc((size_t)NOUTP * 4);
  int* flags  = (int*)alloc((size_t)NWG * 4);
  // Wfuse fp32 temp aliases h3h (prep finishes before lstm_main writes h3h,
  // and lstm_main fully rewrites h3h before dec_kernel reads it).
  float* wftmp = (float*)h3h;

  // ---- prep ----
  pack_mat<<<dim3(2048), dim3(256), 0, stream>>>(Whh1, whh1p, 32);
  pack_mat<<<dim3(2048), dim3(256), 0, stream>>>(Whh2, whh2p, 32);
  pack_mat<<<dim3(2048), dim3(256), 0, stream>>>(Whh3, whh3p, 32);
  pack_mat<<<dim3(2048), dim3(256), 0, stream>>>(Wih2, wih2p, 32);
  pack_mat<<<dim3(2048), dim3(256), 0, stream>>>(Wih3, wih3p, 32);
  pack_wih1<<<dim3(384), dim3(256), 0, stream>>>(Wih1, wih1p);
  wfuse_kernel<<<dim3(4096, 4), dim3(256), 0, stream>>>(Wih1, Wdec, wftmp);
  pack_mat<<<dim3(2048), dim3(256), 0, stream>>>(wftmp, wfusep, 32);
  pack_wdec<<<dim3(88), dim3(256), 0, stream>>>(Wdec, wdecp);
  pack_seed<<<dim3(3072), dim3(256), 0, stream>>>(seed, seedp);
  prep_bias<<<dim3(16), dim3(256), 0, stream>>>(bih1, bhh1, bih2, bhh2, bih3, bhh3,
                                                Wih1, bdec, b1s, b1g, b2, b3, bdecp);
  // ---- recurrence ----
  lstm_main<<<dim3(NWG), dim3(256), 0, stream>>>(
      whh1p, whh2p, whh3p, wih2p, wih3p, wfusep, wih1p, seedp,
      h1b, h2b, h3h, b1s, b1g, b2, b3, flags);
  // ---- batched decoder ----
  dec_kernel<<<dim3(1408), dim3(256), 0, stream>>>(h3h, wdecp, bdecp, (float*)d_out);
}

// Round 2
// 21007.088 us; speedup vs baseline: 3.7704x; 3.7704x over previous
//
#include <hip/hip_runtime.h>
#include <hip/hip_bf16.h>
#include <math.h>

// Problem constants
#define NB    32    // batch
#define NSEED 128
#define NTT   512   // total timesteps (128 seed + 384 gen)
#define NIN   171
#define NINP  192   // padded input dim (6 k-tiles of 32)
#define NH    1024
#define NG    4096  // 4*H
#define NOUT  171
#define NOUTP 176   // padded to 11 n-tiles of 16
#define NWG   256

typedef unsigned short u16;
typedef __attribute__((ext_vector_type(8))) short bf16x8;
typedef __attribute__((ext_vector_type(4))) float f32x4;

__device__ __host__ inline u16 f2bf(float x) {
  union { float f; unsigned u; } v; v.f = x;
  unsigned r = v.u + 0x7FFFu + ((v.u >> 16) & 1u);
  return (u16)(r >> 16);
}

// ---------------------------------------------------------------------------
// Packing: each 4096xK fp32 weight matrix -> MFMA B-fragment blobs (bf16).
// Column permute: WG w owns hidden units j in {4w..4w+3}; packed col
// c = jl*4 + gate  ->  original row r = gate*1024 + w*4 + jl.
// Blob layout: dst[(((kt*256)+nt)*64 + lane)*8 + j] = W[r][kt*32 + (lane>>4)*8 + j]
// ---------------------------------------------------------------------------
__global__ void pack_mat(const float* __restrict__ src, u16* __restrict__ dst, int ktiles) {
  int id = blockIdx.x * 256 + threadIdx.x;
  int total = ktiles * 256 * 64;
  if (id >= total) return;
  int lane = id & 63;
  int nt = (id >> 6) & 255;
  int kt = id >> 14;
  int c = lane & 15, q = lane >> 4;
  int r = (c & 3) * 1024 + nt * 4 + (c >> 2);
  int K = ktiles * 32;
  const float* s = src + (size_t)r * K + kt * 32 + q * 8;
  __attribute__((aligned(16))) u16 o[8];
#pragma unroll
  for (int j = 0; j < 8; ++j) o[j] = f2bf(s[j]);
  *(bf16x8*)(dst + (size_t)id * 8) = *(const bf16x8*)o;
}

// Wih1: [4096 x 171] padded to K=192 (6 ktiles), same permute.
__global__ void pack_wih1(const float* __restrict__ src, u16* __restrict__ dst) {
  int id = blockIdx.x * 256 + threadIdx.x;
  if (id >= 6 * 256 * 64) return;
  int lane = id & 63;
  int nt = (id >> 6) & 255;
  int kt = id >> 14;
  int c = lane & 15, q = lane >> 4;
  int r = (c & 3) * 1024 + nt * 4 + (c >> 2);
  int k0 = kt * 32 + q * 8;
  __attribute__((aligned(16))) u16 o[8];
#pragma unroll
  for (int j = 0; j < 8; ++j) {
    int k = k0 + j;
    o[j] = (k < NIN) ? f2bf(src[(size_t)r * NIN + k]) : (u16)0;
  }
  *(bf16x8*)(dst + (size_t)id * 8) = *(const bf16x8*)o;
}

// Wdec: [171 x 1024] -> B-frags for out = h3 @ Wdec^T, cols padded to 176 (11 ntiles).
__global__ void pack_wdec(const float* __restrict__ src, u16* __restrict__ dst) {
  int id = blockIdx.x * 256 + threadIdx.x;
  if (id >= 32 * 11 * 64) return;
  int lane = id & 63;
  int nt = (id >> 6) % 11;
  int kt = (id >> 6) / 11;
  int c = lane & 15, q = lane >> 4;
  int r = nt * 16 + c;  // output column
  int k0 = kt * 32 + q * 8;
  __attribute__((aligned(16))) u16 o[8];
#pragma unroll
  for (int j = 0; j < 8; ++j) {
    o[j] = (r < NOUT) ? f2bf(src[(size_t)r * NH + k0 + j]) : (u16)0;
  }
  *(bf16x8*)(dst + (size_t)id * 8) = *(const bf16x8*)o;
}

// seed_seq [32][128][171] fp32 -> [t][b][192] bf16, zero padded
__global__ void pack_seed(const float* __restrict__ src, u16* __restrict__ dst) {
  int id = blockIdx.x * 256 + threadIdx.x;
  if (id >= NSEED * NB * NINP) return;
  int kp = id % NINP;
  int b = (id / NINP) % NB;
  int t = id / (NINP * NB);
  float v = (kp < NIN) ? src[((size_t)b * NSEED + t) * NIN + kp] : 0.f;
  dst[id] = f2bf(v);
}

// Wfuse = Wih1 @ Wdec : [4096 x 1024] fp32 (decoder folded into layer-1 input path)
__global__ void wfuse_kernel(const float* __restrict__ wih1, const float* __restrict__ wdec,
                             float* __restrict__ tmp) {
  int n = blockIdx.x;
  int k = blockIdx.y * 256 + threadIdx.x;
  const float* wr = wih1 + (size_t)n * NIN;
  float s = 0.f;
  for (int i = 0; i < NIN; ++i) s += wr[i] * wdec[(size_t)i * NH + k];
  tmp[(size_t)n * NH + k] = s;
}

// biases, permuted to packed column order; b1g additionally folds Wih1 @ bdec
__global__ void prep_bias(const float* bih1, const float* bhh1, const float* bih2, const float* bhh2,
                          const float* bih3, const float* bhh3, const float* __restrict__ wih1,
                          const float* __restrict__ bdec_in,
                          float* b1s, float* b1g, float* b2, float* b3, float* bdecp) {
  int n = blockIdx.x * 256 + threadIdx.x;
  if (n >= NG) return;
  int wgi = n >> 4, c = n & 15;
  int r = (c & 3) * 1024 + wgi * 4 + (c >> 2);
  float v1 = bih1[r] + bhh1[r];
  b1s[n] = v1;
  float bf = 0.f;
  for (int i = 0; i < NIN; ++i) bf += wih1[(size_t)r * NIN + i] * bdec_in[i];
  b1g[n] = v1 + bf;
  b2[n] = bih2[r] + bhh2[r];
  b3[n] = bih3[r] + bhh3[r];
  if (n < NOUTP) bdecp[n] = (n < NOUT) ? bdec_in[n] : 0.f;
}

// ---------------------------------------------------------------------------
// MFMA helpers. KTSTRIDE in u16 elements between consecutive k-tiles of the
// packed B stream. Global packed: 256*64*8 = 131072. LDS slice: 64*8 = 512.
// ---------------------------------------------------------------------------
#define MFMA_BF16 __builtin_amdgcn_mfma_f32_16x16x32_bf16

template<int KTSTRIDE>
__device__ __forceinline__ void mm32_pf(f32x4& d0, f32x4& d1, const u16* wbase,
                                        const u16* __restrict__ x, int rs, int wv, int lane) {
  int m = lane & 15, q = lane >> 4;
  const u16* xa = x + m * rs + q * 8;
  const u16* xb = xa + 16 * rs;
  const u16* wb = wbase + lane * 8;
  bf16x8 w[8];
#pragma unroll
  for (int i = 0; i < 8; ++i) w[i] = *(const bf16x8*)(wb + (size_t)(wv + 4 * i) * KTSTRIDE);
#pragma unroll
  for (int i = 0; i < 8; ++i) {
    int kt = wv + 4 * i;
    bf16x8 a0 = *(const bf16x8*)(xa + kt * 32);
    bf16x8 a1 = *(const bf16x8*)(xb + kt * 32);
    d0 = MFMA_BF16(a0, w[i], d0, 0, 0, 0);
    d1 = MFMA_BF16(a1, w[i], d1, 0, 0, 0);
  }
}

// K=192 (6 ktiles) variant for the seed-phase Wih1 path.
__device__ __forceinline__ void mm6_glb(f32x4& d0, f32x4& d1, const u16* __restrict__ wbase,
                                        const u16* __restrict__ x, int rs, int wv, int lane) {
  int m = lane & 15, q = lane >> 4;
  const u16* xa = x + m * rs + q * 8;
  const u16* xb = xa + 16 * rs;
  const u16* wb = wbase + lane * 8;
#pragma unroll
  for (int i = 0; i < 2; ++i) {
    int kt = wv + 4 * i;
    if (kt >= 6) break;
    bf16x8 w = *(const bf16x8*)(wb + (size_t)kt * 131072);
    bf16x8 a0 = *(const bf16x8*)(xa + kt * 32);
    bf16x8 a1 = *(const bf16x8*)(xb + kt * 32);
    d0 = MFMA_BF16(a0, w, d0, 0, 0, 0);
    d1 = MFMA_BF16(a1, w, d1, 0, 0, 0);
  }
}

// ---------------------------------------------------------------------------
// Main persistent kernel. 256 WGs x 256 threads, 1 WG/CU (LDS-bound).
// LDS holds the three latency-critical (post-barrier) B matrices:
//   slot 0 = wih2, slot 1 = wih3, slot 2 = wfuse   (32 KB each)
// Recurrent (phase A) matmuls run BEFORE the grid barrier (inputs are 3
// stages old), hiding their latency under barrier skew; whh1-3 stay in L2
// (3 MB/XCD footprint).
// ---------------------------------------------------------------------------
__global__ __launch_bounds__(256, 1) void lstm_main(
    const u16* __restrict__ whh1, const u16* __restrict__ whh2, const u16* __restrict__ whh3,
    const u16* __restrict__ wih2, const u16* __restrict__ wih3,
    const u16* __restrict__ wfuse, const u16* __restrict__ wih1,
    const u16* __restrict__ seedp,
    u16* __restrict__ h1b, u16* __restrict__ h2b, u16* __restrict__ h3h,
    const float* __restrict__ b1s, const float* __restrict__ b1g,
    const float* __restrict__ b2, const float* __restrict__ b3,
    int* __restrict__ flags)
{
  __shared__ u16  wlds[3 * 16384];     // 96 KB: wih2 | wih3 | wfuse slices
  __shared__ float red[4][64][8];      // 4-wave split-K reduction (8 KB)
  __shared__ float gbuf[32][16];       // gates (b, packed col)
  __shared__ float cst[3][32][4];      // cell state: layer, batch, local j

  int wg = blockIdx.x;
  int tid = threadIdx.x;
  int wv = tid >> 6, lane = tid & 63;

  // ---- stage phase-B weight slices into LDS (one time) ----
  {
    const u16* srcs[3] = { wih2 + (size_t)wg * 512, wih3 + (size_t)wg * 512,
                           wfuse + (size_t)wg * 512 };
#pragma unroll
    for (int m = 0; m < 3; ++m) {
      for (int i = tid; i < 2048; i += 256) {          // 32 kt * 64 lanes
        int kt = i >> 6, ln = i & 63;
        *(bf16x8*)&wlds[m * 16384 + (kt * 64 + ln) * 8] =
            *(const bf16x8*)(srcs[m] + ((size_t)kt * 16384 + ln) * 8);
      }
    }
    float* cp = &cst[0][0][0];
    for (int i = tid; i < 3 * 32 * 4; i += 256) cp[i] = 0.f;
  }
  __syncthreads();

  // per-thread bias preload (epilogue uses c = tid & 15)
  int c0 = tid & 15;
  float bv_s  = b1s[wg * 16 + c0];
  float bv_g  = b1g[wg * 16 + c0];
  float bv_2  = b2 [wg * 16 + c0];
  float bv_3  = b3 [wg * 16 + c0];

  const u16* whhg[3] = { whh1 + (size_t)wg * 512, whh2 + (size_t)wg * 512,
                         whh3 + (size_t)wg * 512 };
  const u16* wih1g = wih1 + (size_t)wg * 512;

  int ep = 0;  // completed stages
  for (int t = 0; t < NTT; ++t) {
    int par = t & 1, parp = par ^ 1;
    for (int l = 0; l < 3; ++l) {
      f32x4 d0 = {0.f, 0.f, 0.f, 0.f}, d1 = {0.f, 0.f, 0.f, 0.f};
      bool isseed = (t < NSEED);

      // ---- pre-barrier work (inputs >= 3 stages old) ----
      if (l == 0 && isseed)   // seed input term: no barrier dependency at all
        mm6_glb(d0, d1, wih1g, seedp + (size_t)t * NB * NINP, NINP, wv, lane);
      if (t > 0) {            // recurrent term h_l[t-1] @ Whh_l^T
        const u16* hs = (l == 0) ? h1b + (size_t)parp * NB * NH
                     : (l == 1) ? h2b + (size_t)parp * NB * NH
                                : h3h + (size_t)(t - 1) * NB * NH;
        mm32_pf<131072>(d0, d1, whhg[l], hs, NH, wv, lane);
      }

      // ---- grid barrier wait (skip: seed-phase l==0 has no fresh dep) ----
      bool skipwait = (l == 0 && t >= 1 && isseed);
      if (ep > 0 && !skipwait) {
        if (tid < 64) {
          const int* fp = flags + (tid << 2);
          for (;;) {
            int f0 = __hip_atomic_load(fp + 0, __ATOMIC_RELAXED, __HIP_MEMORY_SCOPE_AGENT);
            int f1 = __hip_atomic_load(fp + 1, __ATOMIC_RELAXED, __HIP_MEMORY_SCOPE_AGENT);
            int f2 = __hip_atomic_load(fp + 2, __ATOMIC_RELAXED, __HIP_MEMORY_SCOPE_AGENT);
            int f3 = __hip_atomic_load(fp + 3, __ATOMIC_RELAXED, __HIP_MEMORY_SCOPE_AGENT);
            int mn = min(min(f0, f1), min(f2, f3));
            if (__all(mn >= ep)) break;
            __builtin_amdgcn_s_sleep(2);
          }
          __threadfence();   // acquire: invalidate stale L1/L2 lines
        }
        __syncthreads();
      }

      // ---- post-barrier: fresh input term (B from LDS) ----
      if (l == 0) {
        if (!isseed)  // gen: x = dec(h3[t-1]) folded -> wfuse (LDS slot 2)
          mm32_pf<512>(d0, d1, &wlds[2 * 16384], h3h + (size_t)(t - 1) * NB * NH, NH, wv, lane);
      } else {
        const u16* xs = (l == 1) ? h1b + (size_t)par * NB * NH
                                 : h2b + (size_t)par * NB * NH;
        mm32_pf<512>(d0, d1, &wlds[(l - 1) * 16384], xs, NH, wv, lane);
      }

      // ---- reduce the 4 waves' split-K partials via LDS ----
#pragma unroll
      for (int r = 0; r < 4; ++r) { red[wv][lane][r] = d0[r]; red[wv][lane][4 + r] = d1[r]; }
      __syncthreads();
      {
        int c = tid & 15, brow = tid >> 4;   // brow 0..15
        float bv = (l == 0) ? (isseed ? bv_s : bv_g) : (l == 1) ? bv_2 : bv_3;
        int srcl = ((brow >> 2) << 4) | c;   // D-frag: col=lane&15, row=(lane>>4)*4+reg
#pragma unroll
        for (int mt = 0; mt < 2; ++mt) {
          int b = brow + mt * 16;
          int idx = mt * 4 + (brow & 3);
          gbuf[b][c] = red[0][srcl][idx] + red[1][srcl][idx] +
                       red[2][srcl][idx] + red[3][srcl][idx] + bv;
        }
      }
      __syncthreads();

      // ---- pointwise LSTM cell for our 4 hidden units ----
      if (tid < 128) {
        int b = tid & 31, jl = tid >> 5;
        float gi = gbuf[b][jl * 4 + 0], gf = gbuf[b][jl * 4 + 1];
        float gg = gbuf[b][jl * 4 + 2], go = gbuf[b][jl * 4 + 3];
        float si = 1.f / (1.f + expf(-gi));
        float sf = 1.f / (1.f + expf(-gf));
        float so = 1.f / (1.f + expf(-go));
        float cn = sf * cst[l][b][jl] + si * tanhf(gg);
        cst[l][b][jl] = cn;
        float hn = so * tanhf(cn);
        u16 hb = f2bf(hn);
        size_t col = (size_t)wg * 4 + jl;
        if (l == 0)      h1b[(size_t)par * NB * NH + (size_t)b * NH + col] = hb;
        else if (l == 1) h2b[(size_t)par * NB * NH + (size_t)b * NH + col] = hb;
        else             h3h[(size_t)t * NB * NH + (size_t)b * NH + col] = hb;
      }

      // ---- signal stage completion ----
      __syncthreads();   // drains all waves' stores (vmcnt) before release
      ++ep;
      if (tid == 0)
        __hip_atomic_store(&flags[wg], ep, __ATOMIC_RELEASE, __HIP_MEMORY_SCOPE_AGENT);
    }
  }
}

// ---------------------------------------------------------------------------
// Batched decoder: out[b][t][o] = h3[t] @ Wdec^T + bdec for all 512 steps.
// ---------------------------------------------------------------------------
__global__ __launch_bounds__(256) void dec_kernel(
    const u16* __restrict__ h3h, const u16* __restrict__ wdec,
    const float* __restrict__ bdecp, float* __restrict__ out)
{
  int task = blockIdx.x * 4 + (threadIdx.x >> 6);
  int lane = threadIdx.x & 63;
  int nt = task % 11, rt = task / 11;
  if (rt >= NTT) return;
  int m = lane & 15, q = lane >> 4;
  const u16* xa = h3h + ((size_t)rt * 32 + m) * NH + q * 8;
  const u16* xb = xa + (size_t)16 * NH;
  f32x4 d0 = {0.f, 0.f, 0.f, 0.f}, d1 = {0.f, 0.f, 0.f, 0.f};
  for (int kt = 0; kt < 32; ++kt) {
    bf16x8 bf = *(const bf16x8*)(wdec + ((size_t)(kt * 11 + nt) * 64 + lane) * 8);
    bf16x8 a0 = *(const bf16x8*)(xa + kt * 32);
    bf16x8 a1 = *(const bf16x8*)(xb + kt * 32);
    d0 = MFMA_BF16(a0, bf, d0, 0, 0, 0);
    d1 = MFMA_BF16(a1, bf, d1, 0, 0, 0);
  }
  int o = nt * 16 + m;
  if (o >= NOUT) return;
  float bv = bdecp[o];
#pragma unroll
  for (int reg = 0; reg < 4; ++reg) {
    int row0 = rt * 32 + q * 4 + reg;          // row = t*32 + b
    out[(((size_t)(row0 & 31)) * NTT + (row0 >> 5)) * NOUT + o] = d0[reg] + bv;
    int row1 = row0 + 16;
    out[(((size_t)(row1 & 31)) * NTT + (row1 >> 5)) * NOUT + o] = d1[reg] + bv;
  }
}

// ---------------------------------------------------------------------------
extern "C" void kernel_launch(void* const* d_in, const int* in_sizes, int n_in,
                              void* d_out, int out_size, void* d_ws, size_t ws_size,
                              hipStream_t stream) {
  const float* seed = (const float*)d_in[0];
  const float* Wih1 = (const float*)d_in[1];
  const float* Whh1 = (const float*)d_in[2];
  const float* bih1 = (const float*)d_in[3];
  const float* bhh1 = (const float*)d_in[4];
  const float* Wih2 = (const float*)d_in[5];
  const float* Whh2 = (const float*)d_in[6];
  const float* bih2 = (const float*)d_in[7];
  const float* bhh2 = (const float*)d_in[8];
  const float* Wih3 = (const float*)d_in[9];
  const float* Whh3 = (const float*)d_in[10];
  const float* bih3 = (const float*)d_in[11];
  const float* bhh3 = (const float*)d_in[12];
  const float* Wdec = (const float*)d_in[13];
  const float* bdec = (const float*)d_in[14];

  char* ws = (char*)d_ws;
  size_t off = 0;
  auto alloc = [&](size_t bytes) -> void* {
    void* p = ws + off;
    off += (bytes + 63) & ~(size_t)63;
    return p;
  };
  const size_t BIGPK = (size_t)32 * 256 * 64 * 8 * 2;  // 8.39 MB each
  u16* whh1p  = (u16*)alloc(BIGPK);
  u16* whh2p  = (u16*)alloc(BIGPK);
  u16* whh3p  = (u16*)alloc(BIGPK);
  u16* wih2p  = (u16*)alloc(BIGPK);
  u16* wih3p  = (u16*)alloc(BIGPK);
  u16* wfusep = (u16*)alloc(BIGPK);
  u16* wih1p  = (u16*)alloc((size_t)6 * 256 * 64 * 8 * 2);
  u16* wdecp  = (u16*)alloc((size_t)32 * 11 * 64 * 8 * 2);
  u16* seedp  = (u16*)alloc((size_t)NSEED * NB * NINP * 2);
  u16* h1b    = (u16*)alloc((size_t)2 * NB * NH * 2);
  u16* h2b    = (u16*)alloc((size_t)2 * NB * NH * 2);
  u16* h3h    = (u16*)alloc((size_t)NTT * NB * NH * 2);   // 33.5 MB
  float* b1s  = (float*)alloc((size_t)NG * 4);
  float* b1g  = (float*)alloc((size_t)NG * 4);
  float* b2   = (float*)alloc((size_t)NG * 4);
  float* b3   = (float*)alloc((size_t)NG * 4);
  float* bdecp = (float*)alloc((size_t)NOUTP * 4);
  int* flags  = (int*)alloc((size_t)NWG * 4);
  // Wfuse fp32 temp aliases h3h (prep finishes before lstm_main writes h3h,
  // and lstm_main fully rewrites h3h before dec_kernel reads it).
  float* wftmp = (float*)h3h;

  // ---- prep ----
  pack_mat<<<dim3(2048), dim3(256), 0, stream>>>(Whh1, whh1p, 32);
  pack_mat<<<dim3(2048), dim3(256), 0, stream>>>(Whh2, whh2p, 32);
  pack_mat<<<dim3(2048), dim3(256), 0, stream>>>(Whh3, whh3p, 32);
  pack_mat<<<dim3(2048), dim3(256), 0, stream>>>(Wih2, wih2p, 32);
  pack_mat<<<dim3(2048), dim3(256), 0, stream>>>(Wih3, wih3p, 32);
  pack_wih1<<<dim3(384), dim3(256), 0, stream>>>(Wih1, wih1p);
  wfuse_kernel<<<dim3(4096, 4), dim3(256), 0, stream>>>(Wih1, Wdec, wftmp);
  pack_mat<<<dim3(2048), dim3(256), 0, stream>>>(wftmp, wfusep, 32);
  pack_wdec<<<dim3(88), dim3(256), 0, stream>>>(Wdec, wdecp);
  pack_seed<<<dim3(3072), dim3(256), 0, stream>>>(seed, seedp);
  prep_bias<<<dim3(16), dim3(256), 0, stream>>>(bih1, bhh1, bih2, bhh2, bih3, bhh3,
                                                Wih1, bdec, b1s, b1g, b2, b3, bdecp);
  // ---- recurrence ----
  lstm_main<<<dim3(NWG), dim3(256), 0, stream>>>(
      whh1p, whh2p, whh3p, wih2p, wih3p, wfusep, wih1p, seedp,
      h1b, h2b, h3h, b1s, b1g, b2, b3, flags);
  // ---- batched decoder ----
  dec_kernel<<<dim3(1408), dim3(256), 0, stream>>>(h3h, wdecp, bdecp, (float*)d_out);
}

// Round 3
// 8171.783 us; speedup vs baseline: 9.6925x; 2.5707x over previous
//
#include <hip/hip_runtime.h>
#include <hip/hip_bf16.h>
#include <math.h>

// Problem constants
#define NB    32    // batch
#define NSEED 128
#define NTT   512   // total timesteps (128 seed + 384 gen)
#define NIN   171
#define NINP  192   // padded input dim (6 k-tiles of 32)
#define NH    1024
#define NG    4096  // 4*H
#define NOUT  171
#define NOUTP 176   // padded to 11 n-tiles of 16
#define NWG   256

typedef unsigned short u16;
typedef unsigned int u32;
typedef __attribute__((ext_vector_type(8))) short bf16x8;
typedef __attribute__((ext_vector_type(4))) float f32x4;

__device__ __host__ inline u16 f2bf(float x) {
  union { float f; unsigned u; } v; v.f = x;
  unsigned r = v.u + 0x7FFFu + ((v.u >> 16) & 1u);
  return (u16)(r >> 16);
}

// ---------------------------------------------------------------------------
// Packing kernels (unchanged from R2)
// ---------------------------------------------------------------------------
__global__ void pack_mat(const float* __restrict__ src, u16* __restrict__ dst, int ktiles) {
  int id = blockIdx.x * 256 + threadIdx.x;
  int total = ktiles * 256 * 64;
  if (id >= total) return;
  int lane = id & 63;
  int nt = (id >> 6) & 255;
  int kt = id >> 14;
  int c = lane & 15, q = lane >> 4;
  int r = (c & 3) * 1024 + nt * 4 + (c >> 2);
  int K = ktiles * 32;
  const float* s = src + (size_t)r * K + kt * 32 + q * 8;
  __attribute__((aligned(16))) u16 o[8];
#pragma unroll
  for (int j = 0; j < 8; ++j) o[j] = f2bf(s[j]);
  *(bf16x8*)(dst + (size_t)id * 8) = *(const bf16x8*)o;
}

__global__ void pack_wih1(const float* __restrict__ src, u16* __restrict__ dst) {
  int id = blockIdx.x * 256 + threadIdx.x;
  if (id >= 6 * 256 * 64) return;
  int lane = id & 63;
  int nt = (id >> 6) & 255;
  int kt = id >> 14;
  int c = lane & 15, q = lane >> 4;
  int r = (c & 3) * 1024 + nt * 4 + (c >> 2);
  int k0 = kt * 32 + q * 8;
  __attribute__((aligned(16))) u16 o[8];
#pragma unroll
  for (int j = 0; j < 8; ++j) {
    int k = k0 + j;
    o[j] = (k < NIN) ? f2bf(src[(size_t)r * NIN + k]) : (u16)0;
  }
  *(bf16x8*)(dst + (size_t)id * 8) = *(const bf16x8*)o;
}

__global__ void pack_wdec(const float* __restrict__ src, u16* __restrict__ dst) {
  int id = blockIdx.x * 256 + threadIdx.x;
  if (id >= 32 * 11 * 64) return;
  int lane = id & 63;
  int nt = (id >> 6) % 11;
  int kt = (id >> 6) / 11;
  int c = lane & 15, q = lane >> 4;
  int r = nt * 16 + c;  // output column
  int k0 = kt * 32 + q * 8;
  __attribute__((aligned(16))) u16 o[8];
#pragma unroll
  for (int j = 0; j < 8; ++j) {
    o[j] = (r < NOUT) ? f2bf(src[(size_t)r * NH + k0 + j]) : (u16)0;
  }
  *(bf16x8*)(dst + (size_t)id * 8) = *(const bf16x8*)o;
}

__global__ void pack_seed(const float* __restrict__ src, u16* __restrict__ dst) {
  int id = blockIdx.x * 256 + threadIdx.x;
  if (id >= NSEED * NB * NINP) return;
  int kp = id % NINP;
  int b = (id / NINP) % NB;
  int t = id / (NINP * NB);
  float v = (kp < NIN) ? src[((size_t)b * NSEED + t) * NIN + kp] : 0.f;
  dst[id] = f2bf(v);
}

__global__ void wfuse_kernel(const float* __restrict__ wih1, const float* __restrict__ wdec,
                             float* __restrict__ tmp) {
  int n = blockIdx.x;
  int k = blockIdx.y * 256 + threadIdx.x;
  const float* wr = wih1 + (size_t)n * NIN;
  float s = 0.f;
  for (int i = 0; i < NIN; ++i) s += wr[i] * wdec[(size_t)i * NH + k];
  tmp[(size_t)n * NH + k] = s;
}

__global__ void prep_bias(const float* bih1, const float* bhh1, const float* bih2, const float* bhh2,
                          const float* bih3, const float* bhh3, const float* __restrict__ wih1,
                          const float* __restrict__ bdec_in,
                          float* b1s, float* b1g, float* b2, float* b3, float* bdecp) {
  int n = blockIdx.x * 256 + threadIdx.x;
  if (n >= NG) return;
  int wgi = n >> 4, c = n & 15;
  int r = (c & 3) * 1024 + wgi * 4 + (c >> 2);
  float v1 = bih1[r] + bhh1[r];
  b1s[n] = v1;
  float bf = 0.f;
  for (int i = 0; i < NIN; ++i) bf += wih1[(size_t)r * NIN + i] * bdec_in[i];
  b1g[n] = v1 + bf;
  b2[n] = bih2[r] + bhh2[r];
  b3[n] = bih3[r] + bhh3[r];
  if (n < NOUTP) bdecp[n] = (n < NOUT) ? bdec_in[n] : 0.f;
}

// ---------------------------------------------------------------------------
// Coherent (sc0 sc1) batched A-fragment load: 16x dwordx4 from the two row
// tiles, single trailing vmcnt(0). Bypasses stale L1/L2 -> reads from the
// agent coherent point (L3). Bases must be pre-offset by (m*rs + q*8 + wv*32).
// Offsets i*256 bytes = 4 k-tiles apart (split-K stride for one wave).
// ---------------------------------------------------------------------------
__device__ __forceinline__ void load16_sc1(bf16x8 (&a0)[8], bf16x8 (&a1)[8],
                                           const u16* b0, const u16* b1) {
  asm volatile(
      "global_load_dwordx4 %0, %16, off sc0 sc1\n\t"
      "global_load_dwordx4 %8, %17, off sc0 sc1\n\t"
      "global_load_dwordx4 %1, %16, off offset:256 sc0 sc1\n\t"
      "global_load_dwordx4 %9, %17, off offset:256 sc0 sc1\n\t"
      "global_load_dwordx4 %2, %16, off offset:512 sc0 sc1\n\t"
      "global_load_dwordx4 %10, %17, off offset:512 sc0 sc1\n\t"
      "global_load_dwordx4 %3, %16, off offset:768 sc0 sc1\n\t"
      "global_load_dwordx4 %11, %17, off offset:768 sc0 sc1\n\t"
      "global_load_dwordx4 %4, %16, off offset:1024 sc0 sc1\n\t"
      "global_load_dwordx4 %12, %17, off offset:1024 sc0 sc1\n\t"
      "global_load_dwordx4 %5, %16, off offset:1280 sc0 sc1\n\t"
      "global_load_dwordx4 %13, %17, off offset:1280 sc0 sc1\n\t"
      "global_load_dwordx4 %6, %16, off offset:1536 sc0 sc1\n\t"
      "global_load_dwordx4 %14, %17, off offset:1536 sc0 sc1\n\t"
      "global_load_dwordx4 %7, %16, off offset:1792 sc0 sc1\n\t"
      "global_load_dwordx4 %15, %17, off offset:1792 sc0 sc1\n\t"
      "s_waitcnt vmcnt(0)"
      : "=&v"(a0[0]), "=&v"(a0[1]), "=&v"(a0[2]), "=&v"(a0[3]),
        "=&v"(a0[4]), "=&v"(a0[5]), "=&v"(a0[6]), "=&v"(a0[7]),
        "=&v"(a1[0]), "=&v"(a1[1]), "=&v"(a1[2]), "=&v"(a1[3]),
        "=&v"(a1[4]), "=&v"(a1[5]), "=&v"(a1[6]), "=&v"(a1[7])
      : "v"(b0), "v"(b1)
      : "memory");
}

#define MFMA_BF16 __builtin_amdgcn_mfma_f32_16x16x32_bf16

// K=1024 matmul, B from LDS (fresh-x, post-barrier path). x read coherently.
__device__ __forceinline__ void mm32_lds(f32x4& d0, f32x4& d1, const u16* wl,
                                         const u16* x, int wv, int lane) {
  int m = lane & 15, q = lane >> 4;
  const u16* xa = x + m * NH + q * 8 + wv * 32;
  const u16* xb = xa + 16 * NH;
  bf16x8 a0[8], a1[8];
  load16_sc1(a0, a1, xa, xb);
  const u16* wb = wl + lane * 8;
#pragma unroll
  for (int i = 0; i < 8; ++i) {
    bf16x8 w = *(const bf16x8*)(wb + (size_t)(wv + 4 * i) * 512);
    d0 = MFMA_BF16(a0[i], w, d0, 0, 0, 0);
    d1 = MFMA_BF16(a1[i], w, d1, 0, 0, 0);
  }
}

// K=1024 matmul, B from global (L2-resident weights), x read coherently.
__device__ __forceinline__ void mm32_glb(f32x4& d0, f32x4& d1, const u16* wgb,
                                         const u16* x, int wv, int lane) {
  int m = lane & 15, q = lane >> 4;
  const u16* xa = x + m * NH + q * 8 + wv * 32;
  const u16* xb = xa + 16 * NH;
  const u16* wb = wgb + lane * 8;
  bf16x8 w[8];
#pragma unroll
  for (int i = 0; i < 8; ++i) w[i] = *(const bf16x8*)(wb + (size_t)(wv + 4 * i) * 131072);
  bf16x8 a0[8], a1[8];
  load16_sc1(a0, a1, xa, xb);   // trailing vmcnt(0) also covers the w prefetch
#pragma unroll
  for (int i = 0; i < 8; ++i) {
    d0 = MFMA_BF16(a0[i], w[i], d0, 0, 0, 0);
    d1 = MFMA_BF16(a1[i], w[i], d1, 0, 0, 0);
  }
}

// K=192 (6 ktiles) seed-phase Wih1 path: both operands immutable -> cached.
__device__ __forceinline__ void mm6_glb(f32x4& d0, f32x4& d1, const u16* __restrict__ wbase,
                                        const u16* __restrict__ x, int wv, int lane) {
  int m = lane & 15, q = lane >> 4;
  const u16* xa = x + m * NINP + q * 8;
  const u16* xb = xa + 16 * NINP;
  const u16* wb = wbase + lane * 8;
#pragma unroll
  for (int i = 0; i < 2; ++i) {
    int kt = wv + 4 * i;
    if (kt >= 6) break;
    bf16x8 w = *(const bf16x8*)(wb + (size_t)kt * 131072);
    bf16x8 a0 = *(const bf16x8*)(xa + kt * 32);
    bf16x8 a1 = *(const bf16x8*)(xb + kt * 32);
    d0 = MFMA_BF16(a0, w, d0, 0, 0, 0);
    d1 = MFMA_BF16(a1, w, d1, 0, 0, 0);
  }
}

// ---------------------------------------------------------------------------
// Main persistent kernel. 256 WGs x 256 threads, 1 WG/CU.
// Steady state contains NO cache-maintenance ops (no wbl2/inv):
//  - h exchange: relaxed agent atomic u32 stores (write-through) + sc0 sc1
//    coherent loads. Ordering h-before-flag comes from __syncthreads (vmcnt
//    drain) between them.
//  - weights: immutable, normal loads -> stay L2-resident (never invalidated).
// ---------------------------------------------------------------------------
__global__ __launch_bounds__(256, 1) void lstm_main(
    const u16* __restrict__ whh1, const u16* __restrict__ whh2, const u16* __restrict__ whh3,
    const u16* __restrict__ wih2, const u16* __restrict__ wih3,
    const u16* __restrict__ wfuse, const u16* __restrict__ wih1,
    const u16* __restrict__ seedp,
    u16* __restrict__ h1b, u16* __restrict__ h2b, u16* __restrict__ h3h,
    const float* __restrict__ b1s, const float* __restrict__ b1g,
    const float* __restrict__ b2, const float* __restrict__ b3,
    int* __restrict__ flags)
{
  __shared__ u16  wlds[3 * 16384];     // 96 KB: wih2 | wih3 | wfuse slices
  __shared__ float red[4][64][8];      // 4-wave split-K reduction (8 KB)
  __shared__ float gbuf[32][16];       // gates (b, packed col)
  __shared__ float cst[3][32][4];      // cell state: layer, batch, local j

  int wg = blockIdx.x;
  int tid = threadIdx.x;
  int wv = tid >> 6, lane = tid & 63;

  // ---- stage phase-B weight slices into LDS (one time) ----
  {
    const u16* srcs[3] = { wih2 + (size_t)wg * 512, wih3 + (size_t)wg * 512,
                           wfuse + (size_t)wg * 512 };
#pragma unroll
    for (int m = 0; m < 3; ++m) {
      for (int i = tid; i < 2048; i += 256) {          // 32 kt * 64 lanes
        int kt = i >> 6, ln = i & 63;
        *(bf16x8*)&wlds[m * 16384 + (kt * 64 + ln) * 8] =
            *(const bf16x8*)(srcs[m] + ((size_t)kt * 16384 + ln) * 8);
      }
    }
    float* cp = &cst[0][0][0];
    for (int i = tid; i < 3 * 32 * 4; i += 256) cp[i] = 0.f;
  }
  __syncthreads();

  // per-thread bias preload (epilogue uses c = tid & 15)
  int c0 = tid & 15;
  float bv_s  = b1s[wg * 16 + c0];
  float bv_g  = b1g[wg * 16 + c0];
  float bv_2  = b2 [wg * 16 + c0];
  float bv_3  = b3 [wg * 16 + c0];

  const u16* whhg[3] = { whh1 + (size_t)wg * 512, whh2 + (size_t)wg * 512,
                         whh3 + (size_t)wg * 512 };
  const u16* wih1g = wih1 + (size_t)wg * 512;

  int ep = 0;  // completed stages
  for (int t = 0; t < NTT; ++t) {
    int par = t & 1, parp = par ^ 1;
    for (int l = 0; l < 3; ++l) {
      f32x4 d0 = {0.f, 0.f, 0.f, 0.f}, d1 = {0.f, 0.f, 0.f, 0.f};
      bool isseed = (t < NSEED);

      // ---- pre-barrier work (inputs >= 3 stages old; h via coherent loads) ----
      if (l == 0 && isseed)
        mm6_glb(d0, d1, wih1g, seedp + (size_t)t * NB * NINP, wv, lane);
      if (t > 0) {            // recurrent term h_l[t-1] @ Whh_l^T
        const u16* hs = (l == 0) ? h1b + (size_t)parp * NB * NH
                     : (l == 1) ? h2b + (size_t)parp * NB * NH
                                : h3h + (size_t)(t - 1) * NB * NH;
        mm32_glb(d0, d1, whhg[l], hs, wv, lane);
      }

      // ---- grid barrier wait (fence-free; skip: seed-phase l==0) ----
      bool skipwait = (l == 0 && isseed);
      if (ep > 0 && !skipwait) {
        if (tid < 64) {
          const int* fp = flags + (tid << 2);
          for (;;) {
            int f0 = __hip_atomic_load(fp + 0, __ATOMIC_RELAXED, __HIP_MEMORY_SCOPE_AGENT);
            int f1 = __hip_atomic_load(fp + 1, __ATOMIC_RELAXED, __HIP_MEMORY_SCOPE_AGENT);
            int f2 = __hip_atomic_load(fp + 2, __ATOMIC_RELAXED, __HIP_MEMORY_SCOPE_AGENT);
            int f3 = __hip_atomic_load(fp + 3, __ATOMIC_RELAXED, __HIP_MEMORY_SCOPE_AGENT);
            int mn = min(min(f0, f1), min(f2, f3));
            if (__all(mn >= ep)) break;
            __builtin_amdgcn_s_sleep(1);
          }
        }
        __syncthreads();
      }

      // ---- post-barrier: fresh input term (B from LDS, x coherent) ----
      if (l == 0) {
        if (!isseed)
          mm32_lds(d0, d1, &wlds[2 * 16384], h3h + (size_t)(t - 1) * NB * NH, wv, lane);
      } else {
        const u16* xs = (l == 1) ? h1b + (size_t)par * NB * NH
                                 : h2b + (size_t)par * NB * NH;
        mm32_lds(d0, d1, &wlds[(l - 1) * 16384], xs, wv, lane);
      }

      // ---- reduce the 4 waves' split-K partials via LDS ----
#pragma unroll
      for (int r = 0; r < 4; ++r) { red[wv][lane][r] = d0[r]; red[wv][lane][4 + r] = d1[r]; }
      __syncthreads();
      {
        int c = tid & 15, brow = tid >> 4;   // brow 0..15
        float bv = (l == 0) ? (isseed ? bv_s : bv_g) : (l == 1) ? bv_2 : bv_3;
        int srcl = ((brow >> 2) << 4) | c;   // D-frag: col=lane&15, row=(lane>>4)*4+reg
#pragma unroll
        for (int mt = 0; mt < 2; ++mt) {
          int b = brow + mt * 16;
          int idx = mt * 4 + (brow & 3);
          gbuf[b][c] = red[0][srcl][idx] + red[1][srcl][idx] +
                       red[2][srcl][idx] + red[3][srcl][idx] + bv;
        }
      }
      __syncthreads();

      // ---- pointwise LSTM cell; h exchange via relaxed agent u32 stores ----
      if (tid < 128) {
        int b = tid & 31, jl = tid >> 5;
        float gi = gbuf[b][jl * 4 + 0], gf = gbuf[b][jl * 4 + 1];
        float gg = gbuf[b][jl * 4 + 2], go = gbuf[b][jl * 4 + 3];
        float si = 1.f / (1.f + expf(-gi));
        float sf = 1.f / (1.f + expf(-gf));
        float so = 1.f / (1.f + expf(-go));
        float cn = sf * cst[l][b][jl] + si * tanhf(gg);
        cst[l][b][jl] = cn;
        float hn = so * tanhf(cn);
        unsigned hv = (unsigned)f2bf(hn);
        // pair (jl even, jl odd) lives at lane ^ 32 within the same wave
        unsigned other = (unsigned)__shfl_xor((int)hv, 32, 64);
        if (lane < 32) {
          unsigned val = hv | (other << 16);
          int w01 = tid >> 6;  // 0 -> cols (0,1), 1 -> cols (2,3)
          u16* hdst = (l == 0) ? h1b + (size_t)par * NB * NH
                    : (l == 1) ? h2b + (size_t)par * NB * NH
                               : h3h + (size_t)t * NB * NH;
          u32* hp = (u32*)hdst + (size_t)b * 512 + wg * 2 + w01;
          __hip_atomic_store(hp, val, __ATOMIC_RELAXED, __HIP_MEMORY_SCOPE_AGENT);
        }
      }

      // ---- signal stage completion (relaxed; syncthreads drained vmcnt) ----
      __syncthreads();
      ++ep;
      if (tid == 0)
        __hip_atomic_store(&flags[wg], ep, __ATOMIC_RELAXED, __HIP_MEMORY_SCOPE_AGENT);
    }
  }
}

// ---------------------------------------------------------------------------
// Batched decoder: out[b][t][o] = h3[t] @ Wdec^T + bdec for all 512 steps.
// ---------------------------------------------------------------------------
__global__ __launch_bounds__(256) void dec_kernel(
    const u16* __restrict__ h3h, const u16* __restrict__ wdec,
    const float* __restrict__ bdecp, float* __restrict__ out)
{
  int task = blockIdx.x * 4 + (threadIdx.x >> 6);
  int lane = threadIdx.x & 63;
  int nt = task % 11, rt = task / 11;
  if (rt >= NTT) return;
  int m = lane & 15, q = lane >> 4;
  const u16* xa = h3h + ((size_t)rt * 32 + m) * NH + q * 8;
  const u16* xb = xa + (size_t)16 * NH;
  f32x4 d0 = {0.f, 0.f, 0.f, 0.f}, d1 = {0.f, 0.f, 0.f, 0.f};
  for (int kt = 0; kt < 32; ++kt) {
    bf16x8 bf = *(const bf16x8*)(wdec + ((size_t)(kt * 11 + nt) * 64 + lane) * 8);
    bf16x8 a0 = *(const bf16x8*)(xa + kt * 32);
    bf16x8 a1 = *(const bf16x8*)(xb + kt * 32);
    d0 = MFMA_BF16(a0, bf, d0, 0, 0, 0);
    d1 = MFMA_BF16(a1, bf, d1, 0, 0, 0);
  }
  int o = nt * 16 + m;
  if (o >= NOUT) return;
  float bv = bdecp[o];
#pragma unroll
  for (int reg = 0; reg < 4; ++reg) {
    int row0 = rt * 32 + q * 4 + reg;          // row = t*32 + b
    out[(((size_t)(row0 & 31)) * NTT + (row0 >> 5)) * NOUT + o] = d0[reg] + bv;
    int row1 = row0 + 16;
    out[(((size_t)(row1 & 31)) * NTT + (row1 >> 5)) * NOUT + o] = d1[reg] + bv;
  }
}

// ---------------------------------------------------------------------------
extern "C" void kernel_launch(void* const* d_in, const int* in_sizes, int n_in,
                              void* d_out, int out_size, void* d_ws, size_t ws_size,
                              hipStream_t stream) {
  const float* seed = (const float*)d_in[0];
  const float* Wih1 = (const float*)d_in[1];
  const float* Whh1 = (const float*)d_in[2];
  const float* bih1 = (const float*)d_in[3];
  const float* bhh1 = (const float*)d_in[4];
  const float* Wih2 = (const float*)d_in[5];
  const float* Whh2 = (const float*)d_in[6];
  const float* bih2 = (const float*)d_in[7];
  const float* bhh2 = (const float*)d_in[8];
  const float* Wih3 = (const float*)d_in[9];
  const float* Whh3 = (const float*)d_in[10];
  const float* bih3 = (const float*)d_in[11];
  const float* bhh3 = (const float*)d_in[12];
  const float* Wdec = (const float*)d_in[13];
  const float* bdec = (const float*)d_in[14];

  char* ws = (char*)d_ws;
  size_t off = 0;
  auto alloc = [&](size_t bytes) -> void* {
    void* p = ws + off;
    off += (bytes + 63) & ~(size_t)63;
    return p;
  };
  const size_t BIGPK = (size_t)32 * 256 * 64 * 8 * 2;  // 8.39 MB each
  u16* whh1p  = (u16*)alloc(BIGPK);
  u16* whh2p  = (u16*)alloc(BIGPK);
  u16* whh3p  = (u16*)alloc(BIGPK);
  u16* wih2p  = (u16*)alloc(BIGPK);
  u16* wih3p  = (u16*)alloc(BIGPK);
  u16* wfusep = (u16*)alloc(BIGPK);
  u16* wih1p  = (u16*)alloc((size_t)6 * 256 * 64 * 8 * 2);
  u16* wdecp  = (u16*)alloc((size_t)32 * 11 * 64 * 8 * 2);
  u16* seedp  = (u16*)alloc((size_t)NSEED * NB * NINP * 2);
  u16* h1b    = (u16*)alloc((size_t)2 * NB * NH * 2);
  u16* h2b    = (u16*)alloc((size_t)2 * NB * NH * 2);
  u16* h3h    = (u16*)alloc((size_t)NTT * NB * NH * 2);   // 33.5 MB
  float* b1s  = (float*)alloc((size_t)NG * 4);
  float* b1g  = (float*)alloc((size_t)NG * 4);
  float* b2   = (float*)alloc((size_t)NG * 4);
  float* b3   = (float*)alloc((size_t)NG * 4);
  float* bdecp = (float*)alloc((size_t)NOUTP * 4);
  int* flags  = (int*)alloc((size_t)NWG * 4);
  // Wfuse fp32 temp aliases h3h (prep finishes before lstm_main writes h3h,
  // and lstm_main fully rewrites h3h before dec_kernel reads it).
  float* wftmp = (float*)h3h;

  // ---- prep ----
  pack_mat<<<dim3(2048), dim3(256), 0, stream>>>(Whh1, whh1p, 32);
  pack_mat<<<dim3(2048), dim3(256), 0, stream>>>(Whh2, whh2p, 32);
  pack_mat<<<dim3(2048), dim3(256), 0, stream>>>(Whh3, whh3p, 32);
  pack_mat<<<dim3(2048), dim3(256), 0, stream>>>(Wih2, wih2p, 32);
  pack_mat<<<dim3(2048), dim3(256), 0, stream>>>(Wih3, wih3p, 32);
  pack_wih1<<<dim3(384), dim3(256), 0, stream>>>(Wih1, wih1p);
  wfuse_kernel<<<dim3(4096, 4), dim3(256), 0, stream>>>(Wih1, Wdec, wftmp);
  pack_mat<<<dim3(2048), dim3(256), 0, stream>>>(wftmp, wfusep, 32);
  pack_wdec<<<dim3(88), dim3(256), 0, stream>>>(Wdec, wdecp);
  pack_seed<<<dim3(3072), dim3(256), 0, stream>>>(seed, seedp);
  prep_bias<<<dim3(16), dim3(256), 0, stream>>>(bih1, bhh1, bih2, bhh2, bih3, bhh3,
                                                Wih1, bdec, b1s, b1g, b2, b3, bdecp);
  // ---- recurrence ----
  lstm_main<<<dim3(NWG), dim3(256), 0, stream>>>(
      whh1p, whh2p, whh3p, wih2p, wih3p, wfusep, wih1p, seedp,
      h1b, h2b, h3h, b1s, b1g, b2, b3, flags);
  // ---- batched decoder ----
  dec_kernel<<<dim3(1408), dim3(256), 0, stream>>>(h3h, wdecp, bdecp, (float*)d_out);
}